// Round 17
// baseline (251.775 us; speedup 1.0000x reference)
//
#include <hip/hip_runtime.h>
#include <hip/hip_bf16.h>

// Problem constants (fixed by the reference)
#define BATCH 4
#define TSEQ 2048
#define DM 1024
#define NH 16
#define DH 64
#define MROWS (BATCH * TSEQ)  // 8192
#define CHUNK 64
#define NCHUNK (TSEQ / CHUNK)  // 32

typedef __attribute__((ext_vector_type(8))) short bf16x8;
typedef __attribute__((ext_vector_type(4))) float f32x4;

#define GLOAD16(g, l)                                                        \
    __builtin_amdgcn_global_load_lds(                                        \
        (const __attribute__((address_space(1))) void*)(g),                  \
        (__attribute__((address_space(3))) void*)(l), 16, 0, 0)

// ---------- type helpers ----------
__device__ __forceinline__ float ldf(const float* p) { return *p; }
__device__ __forceinline__ float ldf(const __hip_bfloat16* p) { return __bfloat162float(*p); }
__device__ __forceinline__ void stf(float* p, float v) { *p = v; }
__device__ __forceinline__ void stf(__hip_bfloat16* p, float v) { *p = __float2bfloat16(v); }

// ---------- LDS 64x64 bf16 tile helpers (row = 128 B, XOR swizzle both sides) ----------
__device__ __forceinline__ int swz(int row, int cb) {
    return row * 128 + (cb ^ ((row & 7) << 4));
}
__device__ __forceinline__ bf16x8 ldfrag(const __hip_bfloat16* b, int rowblk, int kf, int lane) {
    const int row = rowblk * 16 + (lane & 15);
    const int cb = kf * 64 + ((lane >> 4) << 4);
    return *(const bf16x8*)((const char*)b + swz(row, cb));
}
__device__ __forceinline__ unsigned short bfbits(float f) {
    __hip_bfloat16 h = __float2bfloat16(f);
    return *(unsigned short*)&h;
}

// ================= bf16 MFMA GEMM (BK=64) =================
template <int NSPLIT>
__global__ __launch_bounds__(256) void gemm_mfma(const __hip_bfloat16* __restrict__ Ah,
                                                 const __hip_bfloat16* __restrict__ BT,
                                                 float* __restrict__ Cf,
                                                 __hip_bfloat16* __restrict__ QhBase,
                                                 __hip_bfloat16* __restrict__ Vh,
                                                 int M, int N, int K) {
    __shared__ __align__(16) __hip_bfloat16 As[128 * 64];
    __shared__ __align__(16) __hip_bfloat16 Bs[128 * 64];
    const int tid = threadIdx.x;
    const int wave = tid >> 6;
    const int lane = tid & 63;
    const int wr = wave >> 1;
    const int wc = wave & 1;

    const int gx = gridDim.x;
    const int nwg = gx * gridDim.y;
    int bid = blockIdx.y * gx + blockIdx.x;
    bid = (bid & 7) * (nwg >> 3) + (bid >> 3);
    const int bx = bid % gx;
    const int by = bid / gx;
    const int wsel = (NSPLIT > 1) ? (bx >> 3) : 0;
    const __hip_bfloat16* BTp = BT + (size_t)wsel * DM * DM;
    const int rowBase = by * 128;
    const int colBase = ((NSPLIT > 1) ? (bx & 7) : bx) * 128;

    f32x4 acc[4][4] = {};

    const size_t Kz = (size_t)K;
    const int sg = (lane & 7) ^ (lane >> 3);
    const int rw0 = wave * 8 + (lane >> 3);

    for (int k0 = 0; k0 < K; k0 += 64) {
#pragma unroll
        for (int i = 0; i < 4; ++i) {
            const int row = rw0 + i * 32;
            GLOAD16(Ah + ((size_t)(rowBase + row) * Kz + k0 + sg * 8),
                    (char*)As + wave * 1024 + i * 4096);
            GLOAD16(BTp + ((size_t)(colBase + row) * Kz + k0 + sg * 8),
                    (char*)Bs + wave * 1024 + i * 4096);
        }
        __syncthreads();

#pragma unroll
        for (int kf = 0; kf < 2; ++kf) {
            bf16x8 af[4], bfr[4];
#pragma unroll
            for (int i = 0; i < 4; ++i) {
                const int ra = wr * 64 + i * 16 + (lane & 15);
                const int rb = wc * 64 + i * 16 + (lane & 15);
                const int slot = kf * 4 + (lane >> 4);
                const int cba = (slot ^ (lane & 7)) << 4;
                af[i] = *(const bf16x8*)((const char*)As + ra * 128 + cba);
                bfr[i] = *(const bf16x8*)((const char*)Bs + rb * 128 + cba);
            }
#pragma unroll
            for (int mi = 0; mi < 4; ++mi)
#pragma unroll
                for (int ni = 0; ni < 4; ++ni)
                    acc[mi][ni] = __builtin_amdgcn_mfma_f32_16x16x32_bf16(af[mi], bfr[ni],
                                                                          acc[mi][ni], 0, 0, 0);
        }
        __syncthreads();
    }

    if (NSPLIT > 1) {
        if (wsel == 1) {
#pragma unroll
            for (int mi = 0; mi < 4; ++mi)
#pragma unroll
                for (int r = 0; r < 4; ++r) {
                    float ss = 0.f;
#pragma unroll
                    for (int ni = 0; ni < 4; ++ni) ss += acc[mi][ni][r] * acc[mi][ni][r];
                    ss += __shfl_xor(ss, 1);
                    ss += __shfl_xor(ss, 2);
                    ss += __shfl_xor(ss, 4);
                    ss += __shfl_xor(ss, 8);
                    const float rn = 1.f / fmaxf(sqrtf(ss), 1e-12f);
#pragma unroll
                    for (int ni = 0; ni < 4; ++ni) acc[mi][ni][r] *= rn;
                }
        }
        __hip_bfloat16* Op = (wsel == 2) ? Vh : (QhBase + (size_t)wsel * ((size_t)M * N));
#pragma unroll
        for (int mi = 0; mi < 4; ++mi)
#pragma unroll
            for (int ni = 0; ni < 4; ++ni) {
                const int col = colBase + wc * 64 + ni * 16 + (lane & 15);
#pragma unroll
                for (int r = 0; r < 4; ++r) {
                    const int row = rowBase + wr * 64 + mi * 16 + (lane >> 4) * 4 + r;
                    Op[(size_t)row * N + col] = __float2bfloat16(acc[mi][ni][r]);
                }
            }
    } else {
#pragma unroll
        for (int mi = 0; mi < 4; ++mi)
#pragma unroll
            for (int ni = 0; ni < 4; ++ni) {
                const int col = colBase + wc * 64 + ni * 16 + (lane & 15);
#pragma unroll
                for (int r = 0; r < 4; ++r) {
                    const int row = rowBase + wr * 64 + mi * 16 + (lane >> 4) * 4 + r;
                    Cf[(size_t)row * N + col] = acc[mi][ni][r];
                }
            }
    }
}

// ---------- conversions ----------
__global__ __launch_bounds__(256) void conv_bf16(const float* __restrict__ in,
                                                 __hip_bfloat16* __restrict__ out, int n8) {
    const int i = blockIdx.x * 256 + threadIdx.x;
    if (i >= n8) return;
    const float4* p = (const float4*)in + (size_t)i * 2;
    float4 a = p[0], b = p[1];
    __hip_bfloat16 t[8] = {__float2bfloat16(a.x), __float2bfloat16(a.y),
                           __float2bfloat16(a.z), __float2bfloat16(a.w),
                           __float2bfloat16(b.x), __float2bfloat16(b.y),
                           __float2bfloat16(b.z), __float2bfloat16(b.w)};
    *(uint4*)(out + (size_t)i * 8) = *(const uint4*)t;
}

// 4 weight transposes fused in one dispatch (z selects the matrix)
__global__ __launch_bounds__(256) void convT4_bf16(const float* __restrict__ W0,
                                                   const float* __restrict__ W1,
                                                   const float* __restrict__ W2,
                                                   const float* __restrict__ W3,
                                                   __hip_bfloat16* __restrict__ T0,
                                                   __hip_bfloat16* __restrict__ T1,
                                                   __hip_bfloat16* __restrict__ T2,
                                                   __hip_bfloat16* __restrict__ T3) {
    __shared__ __hip_bfloat16 tile[64][65];
    const int z = blockIdx.z;
    const float* W = (z == 0) ? W0 : (z == 1) ? W1 : (z == 2) ? W2 : W3;
    __hip_bfloat16* WT = (z == 0) ? T0 : (z == 1) ? T1 : (z == 2) ? T2 : T3;
    const int tid = threadIdx.x;
    const int c = tid & 63;
    const int r4 = tid >> 6;
    const int kb = blockIdx.y * 64;
    const int nb = blockIdx.x * 64;
#pragma unroll
    for (int i = 0; i < 16; ++i) {
        const int r = r4 + i * 4;
        tile[r][c] = __float2bfloat16(W[(size_t)(kb + r) * DM + nb + c]);
    }
    __syncthreads();
#pragma unroll
    for (int i = 0; i < 16; ++i) {
        const int r = r4 + i * 4;
        WT[(size_t)(nb + r) * DM + kb + c] = tile[c][r];
    }
}

// ---------- beta ----------
__global__ __launch_bounds__(256) void beta_kernel(const float* __restrict__ x,
                                                   const float* __restrict__ Wb,
                                                   const float* __restrict__ bb,
                                                   float* __restrict__ beta) {
    const int tid = threadIdx.x;
    const int h = tid % NH;
    const int rl = tid / NH;
    const int row = blockIdx.x * 16 + rl;
    const float* xr = x + (size_t)row * DM;
    float acc = 0.f;
#pragma unroll 8
    for (int k = 0; k < DM; ++k) acc += xr[k] * Wb[k * NH + h];
    acc += bb[h];
    beta[row * NH + h] = 1.f / (1.f + __expf(-acc));
}

// ---------- Kernel A: chunk-local pre-pass (unchanged from R16) ----------
__global__ __launch_bounds__(256) void delta_prepass(const __hip_bfloat16* __restrict__ Knh,
                                                     const __hip_bfloat16* __restrict__ Vh,
                                                     const float* __restrict__ beta,
                                                     __hip_bfloat16* __restrict__ Wtt,
                                                     __hip_bfloat16* __restrict__ Kntt,
                                                     __hip_bfloat16* __restrict__ Utt) {
    const int chunk = blockIdx.x;
    const int bh = blockIdx.y;
    const int b = bh >> 4;
    const int h = bh & 15;
    const int tid = threadIdx.x;
    const int wave = tid >> 6;
    const int lane = tid & 63;
    const int lt = tid >> 2;
    const int j0 = (tid & 3) * 16;
    const int c0 = chunk * CHUNK;
    const size_t tileIdx = (size_t)bh * NCHUNK + chunk;

    __shared__ __align__(16) char smem_raw[17408 + 33792];
    float (*Am2)[68] = reinterpret_cast<float(*)[68]>(smem_raw);
    __hip_bfloat16* Knb = reinterpret_cast<__hip_bfloat16*>(smem_raw + 17408);
    float (*RT)[66] = reinterpret_cast<float(*)[66]>(smem_raw + 17408);
    __shared__ float sbeta[CHUNK];

    const size_t gstride = NH * DH;
    const size_t gbase = (size_t)b * TSEQ * gstride + (size_t)h * DH;
    const __hip_bfloat16* kp = Knh + gbase + (size_t)(c0 + lt) * gstride + j0;
    const __hip_bfloat16* vp = Vh + gbase + (size_t)(c0 + lt) * gstride + j0;

    const uint4 kraw0 = ((const uint4*)kp)[0];
    const uint4 kraw1 = ((const uint4*)kp)[1];
    *(uint4*)((char*)Knb + swz(lt, j0 * 2)) = kraw0;
    *(uint4*)((char*)Knb + swz(lt, j0 * 2 + 16)) = kraw1;
    float kk[16], vv[16];
    {
        const __hip_bfloat16* kb16 = (const __hip_bfloat16*)&kraw0;
#pragma unroll
        for (int e = 0; e < 8; ++e) kk[e] = __bfloat162float(kb16[e]);
        kb16 = (const __hip_bfloat16*)&kraw1;
#pragma unroll
        for (int e = 0; e < 8; ++e) kk[8 + e] = __bfloat162float(kb16[e]);
        const uint4 vraw0 = ((const uint4*)vp)[0];
        const uint4 vraw1 = ((const uint4*)vp)[1];
        const __hip_bfloat16* vb16 = (const __hip_bfloat16*)&vraw0;
#pragma unroll
        for (int e = 0; e < 8; ++e) vv[e] = __bfloat162float(vb16[e]);
        vb16 = (const __hip_bfloat16*)&vraw1;
#pragma unroll
        for (int e = 0; e < 8; ++e) vv[8 + e] = __bfloat162float(vb16[e]);
    }

    if (tid < CHUNK)
        sbeta[tid] = beta[((size_t)(b * TSEQ + c0 + tid)) * NH + h];
    __syncthreads();

    // MFMA A-build: A = Kn . Kn^T
    {
        f32x4 accA[4] = {};
#pragma unroll
        for (int kf = 0; kf < 2; ++kf) {
            bf16x8 ka = ldfrag(Knb, wave, kf, lane);
#pragma unroll
            for (int sb = 0; sb < 4; ++sb)
                accA[sb] = __builtin_amdgcn_mfma_f32_16x16x32_bf16(
                    ka, ldfrag(Knb, sb, kf, lane), accA[sb], 0, 0, 0);
        }
        float bt[4];
#pragma unroll
        for (int r = 0; r < 4; ++r) bt[r] = sbeta[16 * wave + (lane >> 4) * 4 + r];
#pragma unroll
        for (int sb = 0; sb < 4; ++sb)
#pragma unroll
            for (int r = 0; r < 4; ++r) {
                const int row = 16 * wave + (lane >> 4) * 4 + r;
                const int s = 16 * sb + (lane & 15);
                Am2[row][s] = (s < row) ? bt[r] * accA[sb][r] : 0.f;
            }
    }
    __syncthreads();

    // Export Kn TRANSPOSED tile (bf16 swz)
    {
        const int jr = tid >> 2;
        const int tq = (tid & 3) * 16;
        unsigned short pk[16];
#pragma unroll
        for (int i = 0; i < 16; ++i)
            pk[i] = *(const unsigned short*)((const char*)Knb + swz(tq + i, jr * 2));
        char* kt = (char*)Kntt + tileIdx * 8192;
        *(uint4*)(kt + swz(jr, tq * 2)) = *(const uint4*)&pk[0];
        *(uint4*)(kt + swz(jr, tq * 2 + 16)) = *(const uint4*)&pk[8];
    }
    __syncthreads();

    // RT fill (transposed, clobbers Knb)
    {
        const float bl = sbeta[lt];
#pragma unroll
        for (int e = 0; e < 16; ++e) {
            RT[j0 + e][lt] = bl * vv[e];
            RT[64 + j0 + e][lt] = bl * kk[e];
        }
    }
    __syncthreads();

    // Register-resident 4-pivot forward elimination, 16 static steps
    {
        const int c = tid >> 1;
        const int hh = tid & 1;
        float2 ra[16];
#pragma unroll
        for (int lp = 0; lp < 16; ++lp)
            ra[lp] = *(const float2*)&RT[c][4 * lp + 2 * hh];

#pragma unroll
        for (int tt = 0; tt < 16; ++tt) {
            const int t = 4 * tt;
            float2 mine = ra[tt];
            float2 other;
            other.x = __shfl_xor(mine.x, 1);
            other.y = __shfl_xor(mine.y, 1);
            const float r0 = hh ? other.x : mine.x;
            const float r1 = hh ? other.y : mine.y;
            const float r2 = hh ? mine.x : other.x;
            const float r3 = hh ? mine.y : other.y;
            const float4 q1 = *(const float4*)&Am2[t + 1][t];
            const float4 q2 = *(const float4*)&Am2[t + 2][t];
            const float4 q3 = *(const float4*)&Am2[t + 3][t];
            const float p0 = r0;
            const float p1 = r1 - q1.x * p0;
            const float p2 = r2 - q2.x * p0 - q2.y * p1;
            const float p3 = r3 - q3.x * p0 - q3.y * p1 - q3.z * p2;
            ra[tt] = hh ? make_float2(p2, p3) : make_float2(p0, p1);
#pragma unroll
            for (int lp = tt + 1; lp < 16; ++lp) {
                const int pr = 4 * lp + 2 * hh;
                const float4 ca = *(const float4*)&Am2[pr][t];
                const float4 cb = *(const float4*)&Am2[pr + 1][t];
                ra[lp].x -= ca.x * p0 + ca.y * p1 + ca.z * p2 + ca.w * p3;
                ra[lp].y -= cb.x * p0 + cb.y * p1 + cb.z * p2 + cb.w * p3;
            }
        }
#pragma unroll
        for (int lp = 0; lp < 16; ++lp)
            *(float2*)&RT[c][4 * lp + 2 * hh] = ra[lp];
    }
    __syncthreads();

    // write uT + wT tiles (bf16 swz row-major)
    {
        float uu[16], ww[16];
#pragma unroll
        for (int e = 0; e < 16; ++e) {
            uu[e] = RT[j0 + e][lt];
            ww[e] = RT[64 + j0 + e][lt];
        }
        __hip_bfloat16 tu[16], tw[16];
#pragma unroll
        for (int e = 0; e < 16; ++e) {
            tu[e] = __float2bfloat16(uu[e]);
            tw[e] = __float2bfloat16(ww[e]);
        }
        char* ut = (char*)Utt + tileIdx * 8192;
        *(uint4*)(ut + swz(lt, j0 * 2)) = *(const uint4*)&tu[0];
        *(uint4*)(ut + swz(lt, j0 * 2 + 16)) = *(const uint4*)&tu[8];
        char* wt = (char*)Wtt + tileIdx * 8192;
        *(uint4*)(wt + swz(lt, j0 * 2)) = *(const uint4*)&tw[0];
        *(uint4*)(wt + swz(lt, j0 * 2 + 16)) = *(const uint4*)&tw[8];
    }
}

// ---------- Kernel B: thin sequential scan (stage issued EARLY, T14) ----------
__global__ __launch_bounds__(256) void scan_thin(const __hip_bfloat16* __restrict__ Ut_g,
                                                 const __hip_bfloat16* __restrict__ Wt,
                                                 const __hip_bfloat16* __restrict__ Kt,
                                                 __hip_bfloat16* __restrict__ Sg,
                                                 __hip_bfloat16* __restrict__ Utg) {
    const int bh = blockIdx.x;
    const int tid = threadIdx.x;
    const int wave = tid >> 6;
    const int lane = tid & 63;
    const int srow = tid >> 2;
    const int sj0 = (tid & 3) * 16;

    __shared__ __align__(16) __hip_bfloat16 wb[2][64 * 64];
    __shared__ __align__(16) __hip_bfloat16 knT[2][64 * 64];
    __shared__ __align__(16) __hip_bfloat16 ub[2][64 * 64];
    __shared__ __align__(16) __hip_bfloat16 Sb[64 * 64];
    __shared__ __align__(16) __hip_bfloat16 Ut[64 * 64];

    const size_t tileBase = (size_t)bh * NCHUNK;

    auto stage_tiles = [&](int buf, int c) {
        const size_t off = (tileBase + c) * 8192 + wave * 1024 + lane * 16;
        const char* wsrc = (const char*)Wt + off;
        const char* ksrc = (const char*)Kt + off;
        const char* usrc = (const char*)Ut_g + off;
#pragma unroll
        for (int q = 0; q < 2; ++q) {
            GLOAD16(wsrc + q * 4096, (char*)wb[buf] + wave * 1024 + q * 4096);
            GLOAD16(ksrc + q * 4096, (char*)knT[buf] + wave * 1024 + q * 4096);
            GLOAD16(usrc + q * 4096, (char*)ub[buf] + wave * 1024 + q * 4096);
        }
    };

    for (int i = tid; i < 512; i += 256) ((uint4*)Sb)[i] = make_uint4(0, 0, 0, 0);
    stage_tiles(0, 0);

    f32x4 Sreg[4] = {};
    __syncthreads();

    for (int c = 0; c < NCHUNK; ++c) {
        const int cur = c & 1;

        // T14 issue-early: next chunk's loads overlap BOTH MFMA phases.
        // buf cur^1 was last read in iteration c-1 (sealed by its end barrier).
        if (c + 1 < NCHUNK) stage_tiles(cur ^ 1, c + 1);

        {
            uint4 a = *(const uint4*)((const char*)Sb + swz(srow, sj0 * 2));
            uint4 a2 = *(const uint4*)((const char*)Sb + swz(srow, sj0 * 2 + 16));
            __hip_bfloat16* gp = Sg + (tileBase + c) * 4096 + srow * 64 + sj0;
            *(uint4*)gp = a;
            *(uint4*)(gp + 8) = a2;
        }
        f32x4 accU[4] = {};
#pragma unroll
        for (int f = 0; f < 2; ++f) {
            bf16x8 wa = ldfrag(wb[cur], wave, f, lane);
#pragma unroll
            for (int ib = 0; ib < 4; ++ib)
                accU[ib] = __builtin_amdgcn_mfma_f32_16x16x32_bf16(
                    wa, ldfrag(Sb, ib, f, lane), accU[ib], 0, 0, 0);
        }
#pragma unroll
        for (int ib = 0; ib < 4; ++ib) {
            unsigned short pk[4];
#pragma unroll
            for (int r = 0; r < 4; ++r) {
                const int trow = 16 * wave + (lane >> 4) * 4 + r;
                const float uval = __bfloat162float(*(const __hip_bfloat16*)(
                    (const char*)ub[cur] + swz(trow, (16 * ib + (lane & 15)) * 2)));
                pk[r] = bfbits(uval - accU[ib][r]);
            }
            const int irow = 16 * ib + (lane & 15);
            const int tcb = (16 * wave + (lane >> 4) * 4) * 2;
            *(unsigned long long*)((char*)Ut + swz(irow, tcb)) = *(const unsigned long long*)pk;
        }
        __syncthreads();

#pragma unroll
        for (int f = 0; f < 2; ++f) {
            bf16x8 ua = ldfrag(Ut, wave, f, lane);
#pragma unroll
            for (int jb = 0; jb < 4; ++jb)
                Sreg[jb] = __builtin_amdgcn_mfma_f32_16x16x32_bf16(
                    ua, ldfrag(knT[cur], jb, f, lane), Sreg[jb], 0, 0, 0);
        }
        {
            uint4 a = *(const uint4*)((const char*)Ut + swz(srow, sj0 * 2));
            uint4 a2 = *(const uint4*)((const char*)Ut + swz(srow, sj0 * 2 + 16));
            __hip_bfloat16* gp = Utg + (tileBase + c) * 4096 + srow * 64 + sj0;
            *(uint4*)gp = a;
            *(uint4*)(gp + 8) = a2;
        }
#pragma unroll
        for (int jb = 0; jb < 4; ++jb)
#pragma unroll
            for (int r = 0; r < 4; ++r) {
                const int irow = 16 * wave + (lane >> 4) * 4 + r;
                const int j = 16 * jb + (lane & 15);
                *(unsigned short*)((char*)Sb + swz(irow, j * 2)) = bfbits(Sreg[jb][r]);
            }
        __syncthreads();
    }
}

// ---------- Kernel C: parallel output — bf16 in, bf16 out (unchanged) ----------
__global__ __launch_bounds__(256) void delta_output(const __hip_bfloat16* __restrict__ Qh,
                                                    const __hip_bfloat16* __restrict__ Knh,
                                                    const __hip_bfloat16* __restrict__ Sg,
                                                    const __hip_bfloat16* __restrict__ Utg,
                                                    __hip_bfloat16* __restrict__ Ohg) {
    const int c = blockIdx.x;
    const int bh = blockIdx.y;
    const int b = bh >> 4;
    const int h = bh & 15;
    const int tid = threadIdx.x;
    const int wave = tid >> 6;
    const int lane = tid & 63;
    const int srow = tid >> 2;
    const int sj0 = (tid & 3) * 16;

    __shared__ __align__(16) __hip_bfloat16 Qb[64 * 64];
    __shared__ __align__(16) __hip_bfloat16 Knb[64 * 64];
    __shared__ __align__(16) __hip_bfloat16 Sbs[64 * 64];
    __shared__ __align__(16) __hip_bfloat16 Utb[64 * 64];
    __shared__ __align__(16) __hip_bfloat16 SSb[64 * 64];

    const size_t gstride = NH * DH;
    const size_t gbase = (size_t)b * TSEQ * gstride + (size_t)h * DH;
    const size_t cOff = (size_t)(c * CHUNK);
    const size_t tile = ((size_t)bh * NCHUNK + c) * 4096;

    {
        const uint4* qp = (const uint4*)(Qh + gbase + (cOff + srow) * gstride + sj0);
        const uint4* kp = (const uint4*)(Knh + gbase + (cOff + srow) * gstride + sj0);
        *(uint4*)((char*)Qb + swz(srow, sj0 * 2)) = qp[0];
        *(uint4*)((char*)Qb + swz(srow, sj0 * 2 + 16)) = qp[1];
        *(uint4*)((char*)Knb + swz(srow, sj0 * 2)) = kp[0];
        *(uint4*)((char*)Knb + swz(srow, sj0 * 2 + 16)) = kp[1];
        const uint4* sp = (const uint4*)(Sg + tile + srow * 64 + sj0);
        const uint4* upp = (const uint4*)(Utg + tile + srow * 64 + sj0);
        *(uint4*)((char*)Sbs + swz(srow, sj0 * 2)) = sp[0];
        *(uint4*)((char*)Sbs + swz(srow, sj0 * 2 + 16)) = sp[1];
        *(uint4*)((char*)Utb + swz(srow, sj0 * 2)) = upp[0];
        *(uint4*)((char*)Utb + swz(srow, sj0 * 2 + 16)) = upp[1];
    }
    __syncthreads();

    f32x4 ss[4] = {};
    f32x4 accO[4] = {};
#pragma unroll
    for (int f = 0; f < 2; ++f) {
        bf16x8 qa = ldfrag(Qb, wave, f, lane);
#pragma unroll
        for (int sb = 0; sb < 4; ++sb)
            ss[sb] = __builtin_amdgcn_mfma_f32_16x16x32_bf16(
                qa, ldfrag(Knb, sb, f, lane), ss[sb], 0, 0, 0);
#pragma unroll
        for (int ib = 0; ib < 4; ++ib)
            accO[ib] = __builtin_amdgcn_mfma_f32_16x16x32_bf16(
                qa, ldfrag(Sbs, ib, f, lane), accO[ib], 0, 0, 0);
    }
#pragma unroll
    for (int sb = 0; sb < 4; ++sb)
#pragma unroll
        for (int r = 0; r < 4; ++r) {
            const int t = 16 * wave + (lane >> 4) * 4 + r;
            const int s = 16 * sb + (lane & 15);
            const float v = (t >= s) ? ss[sb][r] : 0.f;
            *(unsigned short*)((char*)SSb + swz(t, s * 2)) = bfbits(v);
        }
    __syncthreads();

#pragma unroll
    for (int f = 0; f < 2; ++f) {
        bf16x8 sa = ldfrag(SSb, wave, f, lane);
#pragma unroll
        for (int ib = 0; ib < 4; ++ib)
            accO[ib] = __builtin_amdgcn_mfma_f32_16x16x32_bf16(
                sa, ldfrag(Utb, ib, f, lane), accO[ib], 0, 0, 0);
    }
#pragma unroll
    for (int ib = 0; ib < 4; ++ib)
#pragma unroll
        for (int r = 0; r < 4; ++r) {
            const int t = 16 * wave + (lane >> 4) * 4 + r;
            const int i = 16 * ib + (lane & 15);
            Ohg[gbase + (cOff + t) * gstride + i] = __float2bfloat16(accO[ib][r]);
        }
}

// ---------- legacy fp32 GEMM + sequential scan (fallback path only) ----------
#define BM 64
#define BN 64
#define BK 16

template <typename TA, typename TC>
__global__ __launch_bounds__(256) void gemm_kernel(const TA* __restrict__ A,
                                                   const float* __restrict__ B,
                                                   TC* __restrict__ C,
                                                   int M, int N, int K) {
    __shared__ float As[BK][BM + 1];
    __shared__ float Bs[BK][BN + 1];
    const int tid = threadIdx.x;
    const int tr = tid / 16;
    const int tc = tid % 16;
    const int rowBase = blockIdx.y * BM;
    const int colBase = blockIdx.x * BN;

    float acc[4][4];
#pragma unroll
    for (int m = 0; m < 4; ++m)
#pragma unroll
        for (int n = 0; n < 4; ++n) acc[m][n] = 0.f;

    for (int k0 = 0; k0 < K; k0 += BK) {
#pragma unroll
        for (int i = tid; i < BM * BK; i += 256) {
            int r = i / BK, c = i % BK;
            As[c][r] = ldf(&A[(size_t)(rowBase + r) * K + k0 + c]);
        }
#pragma unroll
        for (int i = tid; i < BK * BN; i += 256) {
            int r = i / BN, c = i % BN;
            Bs[r][c] = B[(size_t)(k0 + r) * N + colBase + c];
        }
        __syncthreads();
#pragma unroll
        for (int kk = 0; kk < BK; ++kk) {
            float a[4], b[4];
#pragma unroll
            for (int m = 0; m < 4; ++m) a[m] = As[kk][tr * 4 + m];
#pragma unroll
            for (int n = 0; n < 4; ++n) b[n] = Bs[kk][tc * 4 + n];
#pragma unroll
            for (int m = 0; m < 4; ++m)
#pragma unroll
                for (int n = 0; n < 4; ++n) acc[m][n] += a[m] * b[n];
        }
        __syncthreads();
    }
#pragma unroll
    for (int m = 0; m < 4; ++m)
#pragma unroll
        for (int n = 0; n < 4; ++n)
            stf(&C[(size_t)(rowBase + tr * 4 + m) * N + colBase + tc * 4 + n], acc[m][n]);
}

template <typename TS>
__global__ __launch_bounds__(64) void scan_kernel(const TS* __restrict__ Q,
                                                  const TS* __restrict__ K,
                                                  const TS* __restrict__ V,
                                                  const float* __restrict__ beta,
                                                  float* __restrict__ O) {
    const int bh = blockIdx.x;
    const int b = bh >> 4;
    const int h = bh & 15;
    const int lane = threadIdx.x;

    float Wrow[64];
#pragma unroll
    for (int j = 0; j < 64; ++j) Wrow[j] = 0.f;

    __shared__ float sk[64];
    __shared__ float sq[64];

    size_t base = ((size_t)b * TSEQ) * (NH * DH) + h * DH + lane;
    int brow = b * TSEQ;

    for (int t = 0; t < TSEQ; ++t, base += NH * DH) {
        float k = ldf(&K[base]);
        float q = ldf(&Q[base]);
        float v = ldf(&V[base]);
        float be = beta[(size_t)(brow + t) * NH + h];

        float ss = k * k;
#pragma unroll
        for (int off = 32; off > 0; off >>= 1) ss += __shfl_xor(ss, off);
        k = k / fmaxf(sqrtf(ss), 1e-12f);

        sk[lane] = k;
        sq[lane] = q;
        __syncthreads();

        float p0 = 0.f, p1 = 0.f, p2 = 0.f, p3 = 0.f;
#pragma unroll
        for (int j = 0; j < 64; j += 4) {
            p0 += Wrow[j + 0] * sk[j + 0];
            p1 += Wrow[j + 1] * sk[j + 1];
            p2 += Wrow[j + 2] * sk[j + 2];
            p3 += Wrow[j + 3] * sk[j + 3];
        }
        const float bei = be * (v - ((p0 + p1) + (p2 + p3)));

        float o0 = 0.f, o1 = 0.f, o2 = 0.f, o3 = 0.f;
#pragma unroll
        for (int j = 0; j < 64; j += 4) {
            Wrow[j + 0] += bei * sk[j + 0]; o0 += Wrow[j + 0] * sq[j + 0];
            Wrow[j + 1] += bei * sk[j + 1]; o1 += Wrow[j + 1] * sq[j + 1];
            Wrow[j + 2] += bei * sk[j + 2]; o2 += Wrow[j + 2] * sq[j + 2];
            Wrow[j + 3] += bei * sk[j + 3]; o3 += Wrow[j + 3] * sq[j + 3];
        }
        O[base] = (o0 + o1) + (o2 + o3);
        __syncthreads();
    }
}

// ---------- launch ----------
extern "C" void kernel_launch(void* const* d_in, const int* in_sizes, int n_in,
                              void* d_out, int out_size, void* d_ws, size_t ws_size,
                              hipStream_t stream) {
    const float* x     = (const float*)d_in[0];
    const float* Wq    = (const float*)d_in[1];
    const float* Wk    = (const float*)d_in[2];
    const float* Wv    = (const float*)d_in[3];
    const float* Wbeta = (const float*)d_in[4];
    const float* bbeta = (const float*)d_in[5];
    const float* Wout  = (const float*)d_in[6];
    float* out = (float*)d_out;

    const size_t projElems = (size_t)MROWS * DM;
    const size_t betaBytes = (size_t)MROWS * NH * 4;
    const size_t f32Bytes  = projElems * 4;   // 32 MiB
    const size_t bf16Bytes = projElems * 2;   // 16 MiB
    const size_t need_f32  = 4 * f32Bytes + betaBytes;

    char* ws = (char*)d_ws;
    size_t off = 0;
    auto alloc = [&](size_t bytes) {
        char* p = ws + off;
        off += (bytes + 255) & ~(size_t)255;
        return (void*)p;
    };

    if (ws_size >= need_f32) {
        float* Qf = (float*)alloc(f32Bytes);    // Qh bf16 [0,16), Knh bf16 [16,32)
        float* Kf = (float*)alloc(f32Bytes);    // Vh bf16 [0,16), WoutT [16,32)
        float* Vf = (float*)alloc(f32Bytes);    // Utt tiles [0,16)
        float* Wmf = (float*)alloc(f32Bytes);   // xh+weights -> Wtt/Kntt tiles -> Oh
        float* betaf = (float*)alloc(betaBytes);

        __hip_bfloat16* Qh    = (__hip_bfloat16*)Qf;
        __hip_bfloat16* Knh   = Qh + projElems;
        __hip_bfloat16* Vh    = (__hip_bfloat16*)Kf;
        __hip_bfloat16* WoutT = (__hip_bfloat16*)((char*)Kf + bf16Bytes);
        __hip_bfloat16* Utt   = (__hip_bfloat16*)Vf;

        __hip_bfloat16* xh  = (__hip_bfloat16*)Wmf;
        __hip_bfloat16* WqT = (__hip_bfloat16*)((char*)Wmf + bf16Bytes);
        __hip_bfloat16* WkT = WqT + (size_t)DM * DM;
        __hip_bfloat16* WvT = WkT + (size_t)DM * DM;

        const int n8 = (int)(projElems / 8);
        conv_bf16<<<dim3(n8 / 256), dim3(256), 0, stream>>>(x, xh, n8);
        // all 4 weight transposes in one dispatch; WoutT produced early
        // (its region is disjoint from Vh, safe before the QKV gemm).
        convT4_bf16<<<dim3(16, 16, 4), dim3(256), 0, stream>>>(Wq, Wk, Wv, Wout,
                                                               WqT, WkT, WvT, WoutT);

        gemm_mfma<3><<<dim3(24, MROWS / 128), dim3(256), 0, stream>>>(xh, WqT, nullptr, Qh, Vh,
                                                                      MROWS, DM, DM);
        beta_kernel<<<dim3(MROWS / 16), dim3(256), 0, stream>>>(x, Wbeta, bbeta, betaf);

        __hip_bfloat16* Wtt  = (__hip_bfloat16*)Wmf;
        __hip_bfloat16* Kntt = (__hip_bfloat16*)((char*)Wmf + bf16Bytes);
        delta_prepass<<<dim3(NCHUNK, BATCH * NH), dim3(256), 0, stream>>>(Knh, Vh, betaf,
                                                                          Wtt, Kntt, Utt);

        __hip_bfloat16* Sg  = (__hip_bfloat16*)d_out;
        __hip_bfloat16* Utg = Sg + (size_t)BATCH * NH * NCHUNK * 4096;
        scan_thin<<<dim3(BATCH * NH), dim3(256), 0, stream>>>(Utt, Wtt, Kntt, Sg, Utg);

        __hip_bfloat16* Oh = (__hip_bfloat16*)Wmf;
        delta_output<<<dim3(NCHUNK, BATCH * NH), dim3(256), 0, stream>>>(Qh, Knh, Sg, Utg, Oh);
        gemm_mfma<1><<<dim3(8, MROWS / 128), dim3(256), 0, stream>>>(Oh, WoutT, out, nullptr,
                                                                     nullptr, MROWS, DM, DM);
    } else {
        __hip_bfloat16* Qh = (__hip_bfloat16*)alloc(bf16Bytes);
        __hip_bfloat16* Kh = (__hip_bfloat16*)alloc(bf16Bytes);
        __hip_bfloat16* Vh = (__hip_bfloat16*)alloc(bf16Bytes);
        float* betaf = (float*)alloc(betaBytes);
        float* Of = (float*)alloc(f32Bytes);

        const dim3 gemmGrid(DM / BN, MROWS / BM);
        gemm_kernel<float, __hip_bfloat16><<<gemmGrid, dim3(256), 0, stream>>>(x, Wq, Qh, MROWS, DM, DM);
        gemm_kernel<float, __hip_bfloat16><<<gemmGrid, dim3(256), 0, stream>>>(x, Wk, Kh, MROWS, DM, DM);
        gemm_kernel<float, __hip_bfloat16><<<gemmGrid, dim3(256), 0, stream>>>(x, Wv, Vh, MROWS, DM, DM);
        beta_kernel<<<dim3(MROWS / 16), dim3(256), 0, stream>>>(x, Wbeta, bbeta, betaf);
        scan_kernel<__hip_bfloat16><<<dim3(BATCH * NH), dim3(64), 0, stream>>>(Qh, Kh, Vh, betaf, Of);
        gemm_kernel<float, float><<<gemmGrid, dim3(256), 0, stream>>>(Of, Wout, out, MROWS, DM, DM);
    }
}

// Round 18
// 238.929 us; speedup vs baseline: 1.0538x; 1.0538x over previous
//
#include <hip/hip_runtime.h>
#include <hip/hip_bf16.h>

// Problem constants (fixed by the reference)
#define BATCH 4
#define TSEQ 2048
#define DM 1024
#define NH 16
#define DH 64
#define MROWS (BATCH * TSEQ)  // 8192
#define CHUNK 64
#define NCHUNK (TSEQ / CHUNK)  // 32

typedef __attribute__((ext_vector_type(8))) short bf16x8;
typedef __attribute__((ext_vector_type(4))) float f32x4;

#define GLOAD16(g, l)                                                        \
    __builtin_amdgcn_global_load_lds(                                        \
        (const __attribute__((address_space(1))) void*)(g),                  \
        (__attribute__((address_space(3))) void*)(l), 16, 0, 0)

// ---------- type helpers ----------
__device__ __forceinline__ float ldf(const float* p) { return *p; }
__device__ __forceinline__ float ldf(const __hip_bfloat16* p) { return __bfloat162float(*p); }
__device__ __forceinline__ void stf(float* p, float v) { *p = v; }
__device__ __forceinline__ void stf(__hip_bfloat16* p, float v) { *p = __float2bfloat16(v); }

// ---------- LDS 64x64 bf16 tile helpers (row = 128 B, XOR swizzle both sides) ----------
__device__ __forceinline__ int swz(int row, int cb) {
    return row * 128 + (cb ^ ((row & 7) << 4));
}
__device__ __forceinline__ bf16x8 ldfrag(const __hip_bfloat16* b, int rowblk, int kf, int lane) {
    const int row = rowblk * 16 + (lane & 15);
    const int cb = kf * 64 + ((lane >> 4) << 4);
    return *(const bf16x8*)((const char*)b + swz(row, cb));
}
__device__ __forceinline__ unsigned short bfbits(float f) {
    __hip_bfloat16 h = __float2bfloat16(f);
    return *(unsigned short*)&h;
}

// ================= bf16 MFMA GEMM (BK=64) =================
template <int NSPLIT>
__global__ __launch_bounds__(256) void gemm_mfma(const __hip_bfloat16* __restrict__ Ah,
                                                 const __hip_bfloat16* __restrict__ BT,
                                                 float* __restrict__ Cf,
                                                 __hip_bfloat16* __restrict__ QhBase,
                                                 __hip_bfloat16* __restrict__ Vh,
                                                 int M, int N, int K) {
    __shared__ __align__(16) __hip_bfloat16 As[128 * 64];
    __shared__ __align__(16) __hip_bfloat16 Bs[128 * 64];
    const int tid = threadIdx.x;
    const int wave = tid >> 6;
    const int lane = tid & 63;
    const int wr = wave >> 1;
    const int wc = wave & 1;

    const int gx = gridDim.x;
    const int nwg = gx * gridDim.y;
    int bid = blockIdx.y * gx + blockIdx.x;
    bid = (bid & 7) * (nwg >> 3) + (bid >> 3);
    const int bx = bid % gx;
    const int by = bid / gx;
    const int wsel = (NSPLIT > 1) ? (bx >> 3) : 0;
    const __hip_bfloat16* BTp = BT + (size_t)wsel * DM * DM;
    const int rowBase = by * 128;
    const int colBase = ((NSPLIT > 1) ? (bx & 7) : bx) * 128;

    f32x4 acc[4][4] = {};

    const size_t Kz = (size_t)K;
    const int sg = (lane & 7) ^ (lane >> 3);
    const int rw0 = wave * 8 + (lane >> 3);

    for (int k0 = 0; k0 < K; k0 += 64) {
#pragma unroll
        for (int i = 0; i < 4; ++i) {
            const int row = rw0 + i * 32;
            GLOAD16(Ah + ((size_t)(rowBase + row) * Kz + k0 + sg * 8),
                    (char*)As + wave * 1024 + i * 4096);
            GLOAD16(BTp + ((size_t)(colBase + row) * Kz + k0 + sg * 8),
                    (char*)Bs + wave * 1024 + i * 4096);
        }
        __syncthreads();

#pragma unroll
        for (int kf = 0; kf < 2; ++kf) {
            bf16x8 af[4], bfr[4];
#pragma unroll
            for (int i = 0; i < 4; ++i) {
                const int ra = wr * 64 + i * 16 + (lane & 15);
                const int rb = wc * 64 + i * 16 + (lane & 15);
                const int slot = kf * 4 + (lane >> 4);
                const int cba = (slot ^ (lane & 7)) << 4;
                af[i] = *(const bf16x8*)((const char*)As + ra * 128 + cba);
                bfr[i] = *(const bf16x8*)((const char*)Bs + rb * 128 + cba);
            }
#pragma unroll
            for (int mi = 0; mi < 4; ++mi)
#pragma unroll
                for (int ni = 0; ni < 4; ++ni)
                    acc[mi][ni] = __builtin_amdgcn_mfma_f32_16x16x32_bf16(af[mi], bfr[ni],
                                                                          acc[mi][ni], 0, 0, 0);
        }
        __syncthreads();
    }

    if (NSPLIT > 1) {
        if (wsel == 1) {
#pragma unroll
            for (int mi = 0; mi < 4; ++mi)
#pragma unroll
                for (int r = 0; r < 4; ++r) {
                    float ss = 0.f;
#pragma unroll
                    for (int ni = 0; ni < 4; ++ni) ss += acc[mi][ni][r] * acc[mi][ni][r];
                    ss += __shfl_xor(ss, 1);
                    ss += __shfl_xor(ss, 2);
                    ss += __shfl_xor(ss, 4);
                    ss += __shfl_xor(ss, 8);
                    const float rn = 1.f / fmaxf(sqrtf(ss), 1e-12f);
#pragma unroll
                    for (int ni = 0; ni < 4; ++ni) acc[mi][ni][r] *= rn;
                }
        }
        __hip_bfloat16* Op = (wsel == 2) ? Vh : (QhBase + (size_t)wsel * ((size_t)M * N));
#pragma unroll
        for (int mi = 0; mi < 4; ++mi)
#pragma unroll
            for (int ni = 0; ni < 4; ++ni) {
                const int col = colBase + wc * 64 + ni * 16 + (lane & 15);
#pragma unroll
                for (int r = 0; r < 4; ++r) {
                    const int row = rowBase + wr * 64 + mi * 16 + (lane >> 4) * 4 + r;
                    Op[(size_t)row * N + col] = __float2bfloat16(acc[mi][ni][r]);
                }
            }
    } else {
#pragma unroll
        for (int mi = 0; mi < 4; ++mi)
#pragma unroll
            for (int ni = 0; ni < 4; ++ni) {
                const int col = colBase + wc * 64 + ni * 16 + (lane & 15);
#pragma unroll
                for (int r = 0; r < 4; ++r) {
                    const int row = rowBase + wr * 64 + mi * 16 + (lane >> 4) * 4 + r;
                    Cf[(size_t)row * N + col] = acc[mi][ni][r];
                }
            }
    }
}

// ---------- conversions ----------
__global__ __launch_bounds__(256) void conv_bf16(const float* __restrict__ in,
                                                 __hip_bfloat16* __restrict__ out, int n8) {
    const int i = blockIdx.x * 256 + threadIdx.x;
    if (i >= n8) return;
    const float4* p = (const float4*)in + (size_t)i * 2;
    float4 a = p[0], b = p[1];
    __hip_bfloat16 t[8] = {__float2bfloat16(a.x), __float2bfloat16(a.y),
                           __float2bfloat16(a.z), __float2bfloat16(a.w),
                           __float2bfloat16(b.x), __float2bfloat16(b.y),
                           __float2bfloat16(b.z), __float2bfloat16(b.w)};
    *(uint4*)(out + (size_t)i * 8) = *(const uint4*)t;
}

// 4 weight transposes fused in one dispatch (z selects the matrix)
__global__ __launch_bounds__(256) void convT4_bf16(const float* __restrict__ W0,
                                                   const float* __restrict__ W1,
                                                   const float* __restrict__ W2,
                                                   const float* __restrict__ W3,
                                                   __hip_bfloat16* __restrict__ T0,
                                                   __hip_bfloat16* __restrict__ T1,
                                                   __hip_bfloat16* __restrict__ T2,
                                                   __hip_bfloat16* __restrict__ T3) {
    __shared__ __hip_bfloat16 tile[64][65];
    const int z = blockIdx.z;
    const float* W = (z == 0) ? W0 : (z == 1) ? W1 : (z == 2) ? W2 : W3;
    __hip_bfloat16* WT = (z == 0) ? T0 : (z == 1) ? T1 : (z == 2) ? T2 : T3;
    const int tid = threadIdx.x;
    const int c = tid & 63;
    const int r4 = tid >> 6;
    const int kb = blockIdx.y * 64;
    const int nb = blockIdx.x * 64;
#pragma unroll
    for (int i = 0; i < 16; ++i) {
        const int r = r4 + i * 4;
        tile[r][c] = __float2bfloat16(W[(size_t)(kb + r) * DM + nb + c]);
    }
    __syncthreads();
#pragma unroll
    for (int i = 0; i < 16; ++i) {
        const int r = r4 + i * 4;
        WT[(size_t)(nb + r) * DM + kb + c] = tile[c][r];
    }
}

// ---------- beta ----------
__global__ __launch_bounds__(256) void beta_kernel(const float* __restrict__ x,
                                                   const float* __restrict__ Wb,
                                                   const float* __restrict__ bb,
                                                   float* __restrict__ beta) {
    const int tid = threadIdx.x;
    const int h = tid % NH;
    const int rl = tid / NH;
    const int row = blockIdx.x * 16 + rl;
    const float* xr = x + (size_t)row * DM;
    float acc = 0.f;
#pragma unroll 8
    for (int k = 0; k < DM; ++k) acc += xr[k] * Wb[k * NH + h];
    acc += bb[h];
    beta[row * NH + h] = 1.f / (1.f + __expf(-acc));
}

// ---------- Kernel A: chunk-local pre-pass ----------
__global__ __launch_bounds__(256) void delta_prepass(const __hip_bfloat16* __restrict__ Knh,
                                                     const __hip_bfloat16* __restrict__ Vh,
                                                     const float* __restrict__ beta,
                                                     __hip_bfloat16* __restrict__ Wtt,
                                                     __hip_bfloat16* __restrict__ Kntt,
                                                     __hip_bfloat16* __restrict__ Utt) {
    const int chunk = blockIdx.x;
    const int bh = blockIdx.y;
    const int b = bh >> 4;
    const int h = bh & 15;
    const int tid = threadIdx.x;
    const int wave = tid >> 6;
    const int lane = tid & 63;
    const int lt = tid >> 2;
    const int j0 = (tid & 3) * 16;
    const int c0 = chunk * CHUNK;
    const size_t tileIdx = (size_t)bh * NCHUNK + chunk;

    __shared__ __align__(16) char smem_raw[17408 + 33792];
    float (*Am2)[68] = reinterpret_cast<float(*)[68]>(smem_raw);
    __hip_bfloat16* Knb = reinterpret_cast<__hip_bfloat16*>(smem_raw + 17408);
    float (*RT)[66] = reinterpret_cast<float(*)[66]>(smem_raw + 17408);
    __shared__ float sbeta[CHUNK];

    const size_t gstride = NH * DH;
    const size_t gbase = (size_t)b * TSEQ * gstride + (size_t)h * DH;
    const __hip_bfloat16* kp = Knh + gbase + (size_t)(c0 + lt) * gstride + j0;
    const __hip_bfloat16* vp = Vh + gbase + (size_t)(c0 + lt) * gstride + j0;

    const uint4 kraw0 = ((const uint4*)kp)[0];
    const uint4 kraw1 = ((const uint4*)kp)[1];
    *(uint4*)((char*)Knb + swz(lt, j0 * 2)) = kraw0;
    *(uint4*)((char*)Knb + swz(lt, j0 * 2 + 16)) = kraw1;
    float kk[16], vv[16];
    {
        const __hip_bfloat16* kb16 = (const __hip_bfloat16*)&kraw0;
#pragma unroll
        for (int e = 0; e < 8; ++e) kk[e] = __bfloat162float(kb16[e]);
        kb16 = (const __hip_bfloat16*)&kraw1;
#pragma unroll
        for (int e = 0; e < 8; ++e) kk[8 + e] = __bfloat162float(kb16[e]);
        const uint4 vraw0 = ((const uint4*)vp)[0];
        const uint4 vraw1 = ((const uint4*)vp)[1];
        const __hip_bfloat16* vb16 = (const __hip_bfloat16*)&vraw0;
#pragma unroll
        for (int e = 0; e < 8; ++e) vv[e] = __bfloat162float(vb16[e]);
        vb16 = (const __hip_bfloat16*)&vraw1;
#pragma unroll
        for (int e = 0; e < 8; ++e) vv[8 + e] = __bfloat162float(vb16[e]);
    }

    if (tid < CHUNK)
        sbeta[tid] = beta[((size_t)(b * TSEQ + c0 + tid)) * NH + h];
    __syncthreads();

    // MFMA A-build: A = Kn . Kn^T
    {
        f32x4 accA[4] = {};
#pragma unroll
        for (int kf = 0; kf < 2; ++kf) {
            bf16x8 ka = ldfrag(Knb, wave, kf, lane);
#pragma unroll
            for (int sb = 0; sb < 4; ++sb)
                accA[sb] = __builtin_amdgcn_mfma_f32_16x16x32_bf16(
                    ka, ldfrag(Knb, sb, kf, lane), accA[sb], 0, 0, 0);
        }
        float bt[4];
#pragma unroll
        for (int r = 0; r < 4; ++r) bt[r] = sbeta[16 * wave + (lane >> 4) * 4 + r];
#pragma unroll
        for (int sb = 0; sb < 4; ++sb)
#pragma unroll
            for (int r = 0; r < 4; ++r) {
                const int row = 16 * wave + (lane >> 4) * 4 + r;
                const int s = 16 * sb + (lane & 15);
                Am2[row][s] = (s < row) ? bt[r] * accA[sb][r] : 0.f;
            }
    }
    __syncthreads();

    // Export Kn TRANSPOSED tile (bf16 swz)
    {
        const int jr = tid >> 2;
        const int tq = (tid & 3) * 16;
        unsigned short pk[16];
#pragma unroll
        for (int i = 0; i < 16; ++i)
            pk[i] = *(const unsigned short*)((const char*)Knb + swz(tq + i, jr * 2));
        char* kt = (char*)Kntt + tileIdx * 8192;
        *(uint4*)(kt + swz(jr, tq * 2)) = *(const uint4*)&pk[0];
        *(uint4*)(kt + swz(jr, tq * 2 + 16)) = *(const uint4*)&pk[8];
    }
    __syncthreads();

    // RT fill (transposed, clobbers Knb)
    {
        const float bl = sbeta[lt];
#pragma unroll
        for (int e = 0; e < 16; ++e) {
            RT[j0 + e][lt] = bl * vv[e];
            RT[64 + j0 + e][lt] = bl * kk[e];
        }
    }
    __syncthreads();

    // Register-resident 4-pivot forward elimination, 16 static steps
    {
        const int c = tid >> 1;
        const int hh = tid & 1;
        float2 ra[16];
#pragma unroll
        for (int lp = 0; lp < 16; ++lp)
            ra[lp] = *(const float2*)&RT[c][4 * lp + 2 * hh];

#pragma unroll
        for (int tt = 0; tt < 16; ++tt) {
            const int t = 4 * tt;
            float2 mine = ra[tt];
            float2 other;
            other.x = __shfl_xor(mine.x, 1);
            other.y = __shfl_xor(mine.y, 1);
            const float r0 = hh ? other.x : mine.x;
            const float r1 = hh ? other.y : mine.y;
            const float r2 = hh ? mine.x : other.x;
            const float r3 = hh ? mine.y : other.y;
            const float4 q1 = *(const float4*)&Am2[t + 1][t];
            const float4 q2 = *(const float4*)&Am2[t + 2][t];
            const float4 q3 = *(const float4*)&Am2[t + 3][t];
            const float p0 = r0;
            const float p1 = r1 - q1.x * p0;
            const float p2 = r2 - q2.x * p0 - q2.y * p1;
            const float p3 = r3 - q3.x * p0 - q3.y * p1 - q3.z * p2;
            ra[tt] = hh ? make_float2(p2, p3) : make_float2(p0, p1);
#pragma unroll
            for (int lp = tt + 1; lp < 16; ++lp) {
                const int pr = 4 * lp + 2 * hh;
                const float4 ca = *(const float4*)&Am2[pr][t];
                const float4 cb = *(const float4*)&Am2[pr + 1][t];
                ra[lp].x -= ca.x * p0 + ca.y * p1 + ca.z * p2 + ca.w * p3;
                ra[lp].y -= cb.x * p0 + cb.y * p1 + cb.z * p2 + cb.w * p3;
            }
        }
#pragma unroll
        for (int lp = 0; lp < 16; ++lp)
            *(float2*)&RT[c][4 * lp + 2 * hh] = ra[lp];
    }
    __syncthreads();

    // write uT + wT tiles (bf16 swz row-major)
    {
        float uu[16], ww[16];
#pragma unroll
        for (int e = 0; e < 16; ++e) {
            uu[e] = RT[j0 + e][lt];
            ww[e] = RT[64 + j0 + e][lt];
        }
        __hip_bfloat16 tu[16], tw[16];
#pragma unroll
        for (int e = 0; e < 16; ++e) {
            tu[e] = __float2bfloat16(uu[e]);
            tw[e] = __float2bfloat16(ww[e]);
        }
        char* ut = (char*)Utt + tileIdx * 8192;
        *(uint4*)(ut + swz(lt, j0 * 2)) = *(const uint4*)&tu[0];
        *(uint4*)(ut + swz(lt, j0 * 2 + 16)) = *(const uint4*)&tu[8];
        char* wt = (char*)Wtt + tileIdx * 8192;
        *(uint4*)(wt + swz(lt, j0 * 2)) = *(const uint4*)&tw[0];
        *(uint4*)(wt + swz(lt, j0 * 2 + 16)) = *(const uint4*)&tw[8];
    }
}

// ---------- Kernel B: thin sequential scan (R16 staging placement: loop tail) ----------
__global__ __launch_bounds__(256) void scan_thin(const __hip_bfloat16* __restrict__ Ut_g,
                                                 const __hip_bfloat16* __restrict__ Wt,
                                                 const __hip_bfloat16* __restrict__ Kt,
                                                 __hip_bfloat16* __restrict__ Sg,
                                                 __hip_bfloat16* __restrict__ Utg) {
    const int bh = blockIdx.x;
    const int tid = threadIdx.x;
    const int wave = tid >> 6;
    const int lane = tid & 63;
    const int srow = tid >> 2;
    const int sj0 = (tid & 3) * 16;

    __shared__ __align__(16) __hip_bfloat16 wb[2][64 * 64];
    __shared__ __align__(16) __hip_bfloat16 knT[2][64 * 64];
    __shared__ __align__(16) __hip_bfloat16 ub[2][64 * 64];
    __shared__ __align__(16) __hip_bfloat16 Sb[64 * 64];
    __shared__ __align__(16) __hip_bfloat16 Ut[64 * 64];

    const size_t tileBase = (size_t)bh * NCHUNK;

    auto stage_tiles = [&](int buf, int c) {
        const size_t off = (tileBase + c) * 8192 + wave * 1024 + lane * 16;
        const char* wsrc = (const char*)Wt + off;
        const char* ksrc = (const char*)Kt + off;
        const char* usrc = (const char*)Ut_g + off;
#pragma unroll
        for (int q = 0; q < 2; ++q) {
            GLOAD16(wsrc + q * 4096, (char*)wb[buf] + wave * 1024 + q * 4096);
            GLOAD16(ksrc + q * 4096, (char*)knT[buf] + wave * 1024 + q * 4096);
            GLOAD16(usrc + q * 4096, (char*)ub[buf] + wave * 1024 + q * 4096);
        }
    };

    for (int i = tid; i < 512; i += 256) ((uint4*)Sb)[i] = make_uint4(0, 0, 0, 0);
    stage_tiles(0, 0);

    f32x4 Sreg[4] = {};
    __syncthreads();

    for (int c = 0; c < NCHUNK; ++c) {
        const int cur = c & 1;

        {
            uint4 a = *(const uint4*)((const char*)Sb + swz(srow, sj0 * 2));
            uint4 a2 = *(const uint4*)((const char*)Sb + swz(srow, sj0 * 2 + 16));
            __hip_bfloat16* gp = Sg + (tileBase + c) * 4096 + srow * 64 + sj0;
            *(uint4*)gp = a;
            *(uint4*)(gp + 8) = a2;
        }
        f32x4 accU[4] = {};
#pragma unroll
        for (int f = 0; f < 2; ++f) {
            bf16x8 wa = ldfrag(wb[cur], wave, f, lane);
#pragma unroll
            for (int ib = 0; ib < 4; ++ib)
                accU[ib] = __builtin_amdgcn_mfma_f32_16x16x32_bf16(
                    wa, ldfrag(Sb, ib, f, lane), accU[ib], 0, 0, 0);
        }
#pragma unroll
        for (int ib = 0; ib < 4; ++ib) {
            unsigned short pk[4];
#pragma unroll
            for (int r = 0; r < 4; ++r) {
                const int trow = 16 * wave + (lane >> 4) * 4 + r;
                const float uval = __bfloat162float(*(const __hip_bfloat16*)(
                    (const char*)ub[cur] + swz(trow, (16 * ib + (lane & 15)) * 2)));
                pk[r] = bfbits(uval - accU[ib][r]);
            }
            const int irow = 16 * ib + (lane & 15);
            const int tcb = (16 * wave + (lane >> 4) * 4) * 2;
            *(unsigned long long*)((char*)Ut + swz(irow, tcb)) = *(const unsigned long long*)pk;
        }
        __syncthreads();

#pragma unroll
        for (int f = 0; f < 2; ++f) {
            bf16x8 ua = ldfrag(Ut, wave, f, lane);
#pragma unroll
            for (int jb = 0; jb < 4; ++jb)
                Sreg[jb] = __builtin_amdgcn_mfma_f32_16x16x32_bf16(
                    ua, ldfrag(knT[cur], jb, f, lane), Sreg[jb], 0, 0, 0);
        }
        {
            uint4 a = *(const uint4*)((const char*)Ut + swz(srow, sj0 * 2));
            uint4 a2 = *(const uint4*)((const char*)Ut + swz(srow, sj0 * 2 + 16));
            __hip_bfloat16* gp = Utg + (tileBase + c) * 4096 + srow * 64 + sj0;
            *(uint4*)gp = a;
            *(uint4*)(gp + 8) = a2;
        }
#pragma unroll
        for (int jb = 0; jb < 4; ++jb)
#pragma unroll
            for (int r = 0; r < 4; ++r) {
                const int irow = 16 * wave + (lane >> 4) * 4 + r;
                const int j = 16 * jb + (lane & 15);
                *(unsigned short*)((char*)Sb + swz(irow, j * 2)) = bfbits(Sreg[jb][r]);
            }
        // stage next chunk at loop TAIL (R16 placement): loads are only drained
        // by the END barrier, fully covered by this iteration's epilogue.
        if (c + 1 < NCHUNK) stage_tiles(cur ^ 1, c + 1);
        __syncthreads();
    }
}

// ---------- Kernel C: parallel output — bf16 in, bf16 out ----------
__global__ __launch_bounds__(256) void delta_output(const __hip_bfloat16* __restrict__ Qh,
                                                    const __hip_bfloat16* __restrict__ Knh,
                                                    const __hip_bfloat16* __restrict__ Sg,
                                                    const __hip_bfloat16* __restrict__ Utg,
                                                    __hip_bfloat16* __restrict__ Ohg) {
    const int c = blockIdx.x;
    const int bh = blockIdx.y;
    const int b = bh >> 4;
    const int h = bh & 15;
    const int tid = threadIdx.x;
    const int wave = tid >> 6;
    const int lane = tid & 63;
    const int srow = tid >> 2;
    const int sj0 = (tid & 3) * 16;

    __shared__ __align__(16) __hip_bfloat16 Qb[64 * 64];
    __shared__ __align__(16) __hip_bfloat16 Knb[64 * 64];
    __shared__ __align__(16) __hip_bfloat16 Sbs[64 * 64];
    __shared__ __align__(16) __hip_bfloat16 Utb[64 * 64];
    __shared__ __align__(16) __hip_bfloat16 SSb[64 * 64];

    const size_t gstride = NH * DH;
    const size_t gbase = (size_t)b * TSEQ * gstride + (size_t)h * DH;
    const size_t cOff = (size_t)(c * CHUNK);
    const size_t tile = ((size_t)bh * NCHUNK + c) * 4096;

    {
        const uint4* qp = (const uint4*)(Qh + gbase + (cOff + srow) * gstride + sj0);
        const uint4* kp = (const uint4*)(Knh + gbase + (cOff + srow) * gstride + sj0);
        *(uint4*)((char*)Qb + swz(srow, sj0 * 2)) = qp[0];
        *(uint4*)((char*)Qb + swz(srow, sj0 * 2 + 16)) = qp[1];
        *(uint4*)((char*)Knb + swz(srow, sj0 * 2)) = kp[0];
        *(uint4*)((char*)Knb + swz(srow, sj0 * 2 + 16)) = kp[1];
        const uint4* sp = (const uint4*)(Sg + tile + srow * 64 + sj0);
        const uint4* upp = (const uint4*)(Utg + tile + srow * 64 + sj0);
        *(uint4*)((char*)Sbs + swz(srow, sj0 * 2)) = sp[0];
        *(uint4*)((char*)Sbs + swz(srow, sj0 * 2 + 16)) = sp[1];
        *(uint4*)((char*)Utb + swz(srow, sj0 * 2)) = upp[0];
        *(uint4*)((char*)Utb + swz(srow, sj0 * 2 + 16)) = upp[1];
    }
    __syncthreads();

    f32x4 ss[4] = {};
    f32x4 accO[4] = {};
#pragma unroll
    for (int f = 0; f < 2; ++f) {
        bf16x8 qa = ldfrag(Qb, wave, f, lane);
#pragma unroll
        for (int sb = 0; sb < 4; ++sb)
            ss[sb] = __builtin_amdgcn_mfma_f32_16x16x32_bf16(
                qa, ldfrag(Knb, sb, f, lane), ss[sb], 0, 0, 0);
#pragma unroll
        for (int ib = 0; ib < 4; ++ib)
            accO[ib] = __builtin_amdgcn_mfma_f32_16x16x32_bf16(
                qa, ldfrag(Sbs, ib, f, lane), accO[ib], 0, 0, 0);
    }
#pragma unroll
    for (int sb = 0; sb < 4; ++sb)
#pragma unroll
        for (int r = 0; r < 4; ++r) {
            const int t = 16 * wave + (lane >> 4) * 4 + r;
            const int s = 16 * sb + (lane & 15);
            const float v = (t >= s) ? ss[sb][r] : 0.f;
            *(unsigned short*)((char*)SSb + swz(t, s * 2)) = bfbits(v);
        }
    __syncthreads();

#pragma unroll
    for (int f = 0; f < 2; ++f) {
        bf16x8 sa = ldfrag(SSb, wave, f, lane);
#pragma unroll
        for (int ib = 0; ib < 4; ++ib)
            accO[ib] = __builtin_amdgcn_mfma_f32_16x16x32_bf16(
                sa, ldfrag(Utb, ib, f, lane), accO[ib], 0, 0, 0);
    }
#pragma unroll
    for (int ib = 0; ib < 4; ++ib)
#pragma unroll
        for (int r = 0; r < 4; ++r) {
            const int t = 16 * wave + (lane >> 4) * 4 + r;
            const int i = 16 * ib + (lane & 15);
            Ohg[gbase + (cOff + t) * gstride + i] = __float2bfloat16(accO[ib][r]);
        }
}

// ---------- legacy fp32 GEMM + sequential scan (fallback path only) ----------
#define BM 64
#define BN 64
#define BK 16

template <typename TA, typename TC>
__global__ __launch_bounds__(256) void gemm_kernel(const TA* __restrict__ A,
                                                   const float* __restrict__ B,
                                                   TC* __restrict__ C,
                                                   int M, int N, int K) {
    __shared__ float As[BK][BM + 1];
    __shared__ float Bs[BK][BN + 1];
    const int tid = threadIdx.x;
    const int tr = tid / 16;
    const int tc = tid % 16;
    const int rowBase = blockIdx.y * BM;
    const int colBase = blockIdx.x * BN;

    float acc[4][4];
#pragma unroll
    for (int m = 0; m < 4; ++m)
#pragma unroll
        for (int n = 0; n < 4; ++n) acc[m][n] = 0.f;

    for (int k0 = 0; k0 < K; k0 += BK) {
#pragma unroll
        for (int i = tid; i < BM * BK; i += 256) {
            int r = i / BK, c = i % BK;
            As[c][r] = ldf(&A[(size_t)(rowBase + r) * K + k0 + c]);
        }
#pragma unroll
        for (int i = tid; i < BK * BN; i += 256) {
            int r = i / BN, c = i % BN;
            Bs[r][c] = B[(size_t)(k0 + r) * N + colBase + c];
        }
        __syncthreads();
#pragma unroll
        for (int kk = 0; kk < BK; ++kk) {
            float a[4], b[4];
#pragma unroll
            for (int m = 0; m < 4; ++m) a[m] = As[kk][tr * 4 + m];
#pragma unroll
            for (int n = 0; n < 4; ++n) b[n] = Bs[kk][tc * 4 + n];
#pragma unroll
            for (int m = 0; m < 4; ++m)
#pragma unroll
                for (int n = 0; n < 4; ++n) acc[m][n] += a[m] * b[n];
        }
        __syncthreads();
    }
#pragma unroll
    for (int m = 0; m < 4; ++m)
#pragma unroll
        for (int n = 0; n < 4; ++n)
            stf(&C[(size_t)(rowBase + tr * 4 + m) * N + colBase + tc * 4 + n], acc[m][n]);
}

template <typename TS>
__global__ __launch_bounds__(64) void scan_kernel(const TS* __restrict__ Q,
                                                  const TS* __restrict__ K,
                                                  const TS* __restrict__ V,
                                                  const float* __restrict__ beta,
                                                  float* __restrict__ O) {
    const int bh = blockIdx.x;
    const int b = bh >> 4;
    const int h = bh & 15;
    const int lane = threadIdx.x;

    float Wrow[64];
#pragma unroll
    for (int j = 0; j < 64; ++j) Wrow[j] = 0.f;

    __shared__ float sk[64];
    __shared__ float sq[64];

    size_t base = ((size_t)b * TSEQ) * (NH * DH) + h * DH + lane;
    int brow = b * TSEQ;

    for (int t = 0; t < TSEQ; ++t, base += NH * DH) {
        float k = ldf(&K[base]);
        float q = ldf(&Q[base]);
        float v = ldf(&V[base]);
        float be = beta[(size_t)(brow + t) * NH + h];

        float ss = k * k;
#pragma unroll
        for (int off = 32; off > 0; off >>= 1) ss += __shfl_xor(ss, off);
        k = k / fmaxf(sqrtf(ss), 1e-12f);

        sk[lane] = k;
        sq[lane] = q;
        __syncthreads();

        float p0 = 0.f, p1 = 0.f, p2 = 0.f, p3 = 0.f;
#pragma unroll
        for (int j = 0; j < 64; j += 4) {
            p0 += Wrow[j + 0] * sk[j + 0];
            p1 += Wrow[j + 1] * sk[j + 1];
            p2 += Wrow[j + 2] * sk[j + 2];
            p3 += Wrow[j + 3] * sk[j + 3];
        }
        const float bei = be * (v - ((p0 + p1) + (p2 + p3)));

        float o0 = 0.f, o1 = 0.f, o2 = 0.f, o3 = 0.f;
#pragma unroll
        for (int j = 0; j < 64; j += 4) {
            Wrow[j + 0] += bei * sk[j + 0]; o0 += Wrow[j + 0] * sq[j + 0];
            Wrow[j + 1] += bei * sk[j + 1]; o1 += Wrow[j + 1] * sq[j + 1];
            Wrow[j + 2] += bei * sk[j + 2]; o2 += Wrow[j + 2] * sq[j + 2];
            Wrow[j + 3] += bei * sk[j + 3]; o3 += Wrow[j + 3] * sq[j + 3];
        }
        O[base] = (o0 + o1) + (o2 + o3);
        __syncthreads();
    }
}

// ---------- launch ----------
extern "C" void kernel_launch(void* const* d_in, const int* in_sizes, int n_in,
                              void* d_out, int out_size, void* d_ws, size_t ws_size,
                              hipStream_t stream) {
    const float* x     = (const float*)d_in[0];
    const float* Wq    = (const float*)d_in[1];
    const float* Wk    = (const float*)d_in[2];
    const float* Wv    = (const float*)d_in[3];
    const float* Wbeta = (const float*)d_in[4];
    const float* bbeta = (const float*)d_in[5];
    const float* Wout  = (const float*)d_in[6];
    float* out = (float*)d_out;

    const size_t projElems = (size_t)MROWS * DM;
    const size_t betaBytes = (size_t)MROWS * NH * 4;
    const size_t f32Bytes  = projElems * 4;   // 32 MiB
    const size_t bf16Bytes = projElems * 2;   // 16 MiB
    const size_t need_f32  = 4 * f32Bytes + betaBytes;

    char* ws = (char*)d_ws;
    size_t off = 0;
    auto alloc = [&](size_t bytes) {
        char* p = ws + off;
        off += (bytes + 255) & ~(size_t)255;
        return (void*)p;
    };

    if (ws_size >= need_f32) {
        float* Qf = (float*)alloc(f32Bytes);    // Qh bf16 [0,16), Knh bf16 [16,32)
        float* Kf = (float*)alloc(f32Bytes);    // Vh bf16 [0,16), WoutT [16,32)
        float* Vf = (float*)alloc(f32Bytes);    // Utt tiles [0,16)
        float* Wmf = (float*)alloc(f32Bytes);   // xh+weights -> Wtt/Kntt tiles -> Oh
        float* betaf = (float*)alloc(betaBytes);

        __hip_bfloat16* Qh    = (__hip_bfloat16*)Qf;
        __hip_bfloat16* Knh   = Qh + projElems;
        __hip_bfloat16* Vh    = (__hip_bfloat16*)Kf;
        __hip_bfloat16* WoutT = (__hip_bfloat16*)((char*)Kf + bf16Bytes);
        __hip_bfloat16* Utt   = (__hip_bfloat16*)Vf;

        __hip_bfloat16* xh  = (__hip_bfloat16*)Wmf;
        __hip_bfloat16* WqT = (__hip_bfloat16*)((char*)Wmf + bf16Bytes);
        __hip_bfloat16* WkT = WqT + (size_t)DM * DM;
        __hip_bfloat16* WvT = WkT + (size_t)DM * DM;

        const int n8 = (int)(projElems / 8);
        conv_bf16<<<dim3(n8 / 256), dim3(256), 0, stream>>>(x, xh, n8);
        convT4_bf16<<<dim3(16, 16, 4), dim3(256), 0, stream>>>(Wq, Wk, Wv, Wout,
                                                               WqT, WkT, WvT, WoutT);

        gemm_mfma<3><<<dim3(24, MROWS / 128), dim3(256), 0, stream>>>(xh, WqT, nullptr, Qh, Vh,
                                                                      MROWS, DM, DM);
        beta_kernel<<<dim3(MROWS / 16), dim3(256), 0, stream>>>(x, Wbeta, bbeta, betaf);

        __hip_bfloat16* Wtt  = (__hip_bfloat16*)Wmf;
        __hip_bfloat16* Kntt = (__hip_bfloat16*)((char*)Wmf + bf16Bytes);
        delta_prepass<<<dim3(NCHUNK, BATCH * NH), dim3(256), 0, stream>>>(Knh, Vh, betaf,
                                                                          Wtt, Kntt, Utt);

        __hip_bfloat16* Sg  = (__hip_bfloat16*)d_out;
        __hip_bfloat16* Utg = Sg + (size_t)BATCH * NH * NCHUNK * 4096;
        scan_thin<<<dim3(BATCH * NH), dim3(256), 0, stream>>>(Utt, Wtt, Kntt, Sg, Utg);

        __hip_bfloat16* Oh = (__hip_bfloat16*)Wmf;
        delta_output<<<dim3(NCHUNK, BATCH * NH), dim3(256), 0, stream>>>(Qh, Knh, Sg, Utg, Oh);
        gemm_mfma<1><<<dim3(8, MROWS / 128), dim3(256), 0, stream>>>(Oh, WoutT, out, nullptr,
                                                                     nullptr, MROWS, DM, DM);
    } else {
        __hip_bfloat16* Qh = (__hip_bfloat16*)alloc(bf16Bytes);
        __hip_bfloat16* Kh = (__hip_bfloat16*)alloc(bf16Bytes);
        __hip_bfloat16* Vh = (__hip_bfloat16*)alloc(bf16Bytes);
        float* betaf = (float*)alloc(betaBytes);
        float* Of = (float*)alloc(f32Bytes);

        const dim3 gemmGrid(DM / BN, MROWS / BM);
        gemm_kernel<float, __hip_bfloat16><<<gemmGrid, dim3(256), 0, stream>>>(x, Wq, Qh, MROWS, DM, DM);
        gemm_kernel<float, __hip_bfloat16><<<gemmGrid, dim3(256), 0, stream>>>(x, Wk, Kh, MROWS, DM, DM);
        gemm_kernel<float, __hip_bfloat16><<<gemmGrid, dim3(256), 0, stream>>>(x, Wv, Vh, MROWS, DM, DM);
        beta_kernel<<<dim3(MROWS / 16), dim3(256), 0, stream>>>(x, Wbeta, bbeta, betaf);
        scan_kernel<__hip_bfloat16><<<dim3(BATCH * NH), dim3(64), 0, stream>>>(Qh, Kh, Vh, betaf, Of);
        gemm_kernel<float, float><<<gemmGrid, dim3(256), 0, stream>>>(Of, Wout, out, MROWS, DM, DM);
    }
}